// Round 1
// baseline (1619.419 us; speedup 1.0000x reference)
//
#include <hip/hip_runtime.h>
#include <hip/hip_bf16.h>

// Problem constants
#define B_    8
#define F_    16
#define NP_   196
#define SEQ_  3137        // 1 + F_*NP_
#define H_    8
#define DH_   64
#define BH_   64          // B_*H_
#define M_    25096       // B_*SEQ_
#define DIM_  512
#define NQKV_ 1536

// workspace layout (in floats)
#define QOFF  ((size_t)0)
#define KOFF  ((size_t)12849152)          // BH_*SEQ_*DH_
#define VOFF  ((size_t)2*12849152)
#define AOFF  ((size_t)3*12849152)

// ---------------------------------------------------------------------------
// K1: qkv = x @ Wqkv, scatter into q/k/v [bh][t][d] layout, q scaled by 1/8.
// Tiled fp32 GEMM: 64x64 tile, BK=16, 256 threads, 4x4 per thread.
// ---------------------------------------------------------------------------
__global__ __launch_bounds__(256) void qkv_gemm_kernel(
    const float* __restrict__ x, const float* __restrict__ w,
    float* __restrict__ ws) {
  __shared__ float As[16][65];   // [k][m], padded to kill write conflicts
  __shared__ float Bs[16][64];   // [k][n]
  const int tid = threadIdx.x;
  const int ty = tid >> 4, tx = tid & 15;
  const int m0 = blockIdx.x * 64;
  const int n0 = blockIdx.y * 64;
  float acc[4][4] = {};

  for (int k0 = 0; k0 < DIM_; k0 += 16) {
#pragma unroll
    for (int l = 0; l < 4; ++l) {
      int idx = tid + l * 256;
      int r = idx >> 4, c = idx & 15;
      int gr = m0 + r;
      As[c][r] = (gr < M_) ? x[(size_t)gr * DIM_ + k0 + c] : 0.f;
    }
#pragma unroll
    for (int l = 0; l < 4; ++l) {
      int r = l * 4 + (tid >> 6), c = tid & 63;
      Bs[r][c] = w[(size_t)(k0 + r) * NQKV_ + n0 + c];
    }
    __syncthreads();
#pragma unroll
    for (int kk = 0; kk < 16; ++kk) {
      float a0 = As[kk][ty], a1 = As[kk][ty + 16], a2 = As[kk][ty + 32], a3 = As[kk][ty + 48];
      float b0 = Bs[kk][tx], b1 = Bs[kk][tx + 16], b2 = Bs[kk][tx + 32], b3 = Bs[kk][tx + 48];
      acc[0][0] += a0 * b0; acc[0][1] += a0 * b1; acc[0][2] += a0 * b2; acc[0][3] += a0 * b3;
      acc[1][0] += a1 * b0; acc[1][1] += a1 * b1; acc[1][2] += a1 * b2; acc[1][3] += a1 * b3;
      acc[2][0] += a2 * b0; acc[2][1] += a2 * b1; acc[2][2] += a2 * b2; acc[2][3] += a2 * b3;
      acc[3][0] += a3 * b0; acc[3][1] += a3 * b1; acc[3][2] += a3 * b2; acc[3][3] += a3 * b3;
    }
    __syncthreads();
  }

  // scatter: col c -> which(q/k/v) = c>>9, head = (c>>6)&7, d = c&63
#pragma unroll
  for (int i = 0; i < 4; ++i) {
    int gr = m0 + ty + i * 16;
    if (gr >= M_) continue;
    int b = gr / SEQ_;
    int t = gr - b * SEQ_;
#pragma unroll
    for (int j = 0; j < 4; ++j) {
      int c = n0 + tx + j * 16;
      int which = c >> 9;
      int h = (c >> 6) & 7;
      int d = c & 63;
      float v = acc[i][j];
      if (which == 0) v *= 0.125f;  // dh^-0.5
      size_t off = (size_t)which * 12849152 +
                   ((size_t)((b * H_ + h) * SEQ_ + t)) * DH_ + d;
      ws[off] = v;
    }
  }
}

// ---------------------------------------------------------------------------
// K2: CLS attention. One block per (b,h); scores over all 3137 keys in LDS.
// ---------------------------------------------------------------------------
__global__ __launch_bounds__(256) void cls_attn_kernel(
    const float* __restrict__ qw, const float* __restrict__ kw,
    const float* __restrict__ vw, float* __restrict__ attn) {
  const int bh = blockIdx.x;
  const int b = bh >> 3, h = bh & 7;
  const int tid = threadIdx.x;
  __shared__ float qs[64];
  __shared__ float s[SEQ_];
  __shared__ float red[256];

  if (tid < 16)
    ((float4*)qs)[tid] = ((const float4*)(qw + (size_t)bh * SEQ_ * DH_))[tid];
  __syncthreads();

  float lmax = -1e30f;
  for (int j = tid; j < SEQ_; j += 256) {
    const float4* kr = (const float4*)(kw + ((size_t)bh * SEQ_ + j) * DH_);
    float sc = 0.f;
#pragma unroll
    for (int i = 0; i < 16; ++i) {
      float4 kk = kr[i];
      sc += qs[4 * i] * kk.x + qs[4 * i + 1] * kk.y + qs[4 * i + 2] * kk.z + qs[4 * i + 3] * kk.w;
    }
    s[j] = sc;
    lmax = fmaxf(lmax, sc);
  }
  red[tid] = lmax; __syncthreads();
  for (int st = 128; st > 0; st >>= 1) {
    if (tid < st) red[tid] = fmaxf(red[tid], red[tid + st]);
    __syncthreads();
  }
  float m = red[0]; __syncthreads();

  float lsum = 0.f;
  for (int j = tid; j < SEQ_; j += 256) {
    float p = __expf(s[j] - m);
    s[j] = p;
    lsum += p;
  }
  red[tid] = lsum; __syncthreads();
  for (int st = 128; st > 0; st >>= 1) {
    if (tid < st) red[tid] += red[tid + st];
    __syncthreads();
  }
  float l = red[0]; __syncthreads();

  const int d = tid & 63, c = tid >> 6;
  float a = 0.f;
  for (int j = c; j < SEQ_; j += 4)
    a += s[j] * vw[((size_t)bh * SEQ_ + j) * DH_ + d];
  red[tid] = a; __syncthreads();
  if (tid < 64) {
    float o = (red[tid] + red[64 + tid] + red[128 + tid] + red[192 + tid]) / l;
    attn[(size_t)(b * SEQ_) * DIM_ + h * DH_ + tid] = o;
  }
}

// ---------------------------------------------------------------------------
// K3: frame attention. One block per (bh, frame). 256 threads, one query each
// (196 active). Keys = CLS + 196 frame keys, tiled by 64 into LDS. Online
// softmax in 16-key register sub-tiles (all statically indexed).
// ---------------------------------------------------------------------------
__global__ __launch_bounds__(256) void frame_attn_kernel(
    const float* __restrict__ qw, const float* __restrict__ kw,
    const float* __restrict__ vw, float* __restrict__ attn) {
  const int bx = blockIdx.x;
  const int bh = bx >> 4, fi = bx & 15;
  const int b = bh >> 3, h = bh & 7;
  const int tid = threadIdx.x;
  const bool active = tid < NP_;
  const int q = active ? tid : 0;
  const int tok = 1 + fi * NP_ + q;
  const int NK = NP_ + 1;  // 197

  __shared__ float Ks[64][64];
  __shared__ float Vs[64][64];

  float4 qv[16];
  {
    const float4* qp = (const float4*)(qw + ((size_t)bh * SEQ_ + tok) * DH_);
#pragma unroll
    for (int i = 0; i < 16; ++i) qv[i] = qp[i];
  }
  float acc[64];
#pragma unroll
  for (int d = 0; d < 64; ++d) acc[d] = 0.f;
  float m = -1e30f, l = 0.f;

  for (int j0 = 0; j0 < NK; j0 += 64) {
    const int nk = min(64, NK - j0);
    for (int idx = tid; idx < nk * 16; idx += 256) {
      int jj = idx >> 4, dq = idx & 15;
      int jg = j0 + jj;
      size_t row = (jg == 0) ? ((size_t)bh * SEQ_)
                             : ((size_t)bh * SEQ_ + 1 + fi * NP_ + jg - 1);
      ((float4*)Ks)[jj * 16 + dq] = ((const float4*)(kw + row * DH_))[dq];
      ((float4*)Vs)[jj * 16 + dq] = ((const float4*)(vw + row * DH_))[dq];
    }
    __syncthreads();

#pragma unroll
    for (int sub = 0; sub < 4; ++sub) {
      if (j0 + sub * 16 < NK) {
        float s[16];
        float tmax = -1e30f;
#pragma unroll
        for (int u = 0; u < 16; ++u) {
          int jj = sub * 16 + u;
          const float4* krow = (const float4*)Ks[jj];
          float sc = 0.f;
#pragma unroll
          for (int i = 0; i < 16; ++i) {
            float4 kk = krow[i];
            sc += qv[i].x * kk.x + qv[i].y * kk.y + qv[i].z * kk.z + qv[i].w * kk.w;
          }
          sc = (j0 + jj < NK) ? sc : -1e30f;
          s[u] = sc;
          tmax = fmaxf(tmax, sc);
        }
        float mn = fmaxf(m, tmax);
        float corr = __expf(m - mn);
        l *= corr;
#pragma unroll
        for (int d = 0; d < 64; ++d) acc[d] *= corr;
#pragma unroll
        for (int u = 0; u < 16; ++u) {
          int jj = sub * 16 + u;
          float p = __expf(s[u] - mn);
          l += p;
          const float4* vrow = (const float4*)Vs[jj];
#pragma unroll
          for (int i = 0; i < 16; ++i) {
            float4 vv = vrow[i];
            acc[4 * i + 0] += p * vv.x;
            acc[4 * i + 1] += p * vv.y;
            acc[4 * i + 2] += p * vv.z;
            acc[4 * i + 3] += p * vv.w;
          }
        }
        m = mn;
      }
    }
    __syncthreads();
  }

  if (active) {
    float inv = 1.f / l;
    float* op = attn + ((size_t)(b * SEQ_) + tok) * DIM_ + h * DH_;
#pragma unroll
    for (int d = 0; d < 64; ++d) op[d] = acc[d] * inv;
  }
}

// ---------------------------------------------------------------------------
// K4: out = attn @ Wout + bout. Same tiled fp32 GEMM, N=512.
// ---------------------------------------------------------------------------
__global__ __launch_bounds__(256) void out_gemm_kernel(
    const float* __restrict__ a, const float* __restrict__ w,
    const float* __restrict__ bias, float* __restrict__ out) {
  __shared__ float As[16][65];
  __shared__ float Bs[16][64];
  const int tid = threadIdx.x;
  const int ty = tid >> 4, tx = tid & 15;
  const int m0 = blockIdx.x * 64;
  const int n0 = blockIdx.y * 64;
  float acc[4][4] = {};

  for (int k0 = 0; k0 < DIM_; k0 += 16) {
#pragma unroll
    for (int l = 0; l < 4; ++l) {
      int idx = tid + l * 256;
      int r = idx >> 4, c = idx & 15;
      int gr = m0 + r;
      As[c][r] = (gr < M_) ? a[(size_t)gr * DIM_ + k0 + c] : 0.f;
    }
#pragma unroll
    for (int l = 0; l < 4; ++l) {
      int r = l * 4 + (tid >> 6), c = tid & 63;
      Bs[r][c] = w[(size_t)(k0 + r) * DIM_ + n0 + c];
    }
    __syncthreads();
#pragma unroll
    for (int kk = 0; kk < 16; ++kk) {
      float a0 = As[kk][ty], a1 = As[kk][ty + 16], a2 = As[kk][ty + 32], a3 = As[kk][ty + 48];
      float b0 = Bs[kk][tx], b1 = Bs[kk][tx + 16], b2 = Bs[kk][tx + 32], b3 = Bs[kk][tx + 48];
      acc[0][0] += a0 * b0; acc[0][1] += a0 * b1; acc[0][2] += a0 * b2; acc[0][3] += a0 * b3;
      acc[1][0] += a1 * b0; acc[1][1] += a1 * b1; acc[1][2] += a1 * b2; acc[1][3] += a1 * b3;
      acc[2][0] += a2 * b0; acc[2][1] += a2 * b1; acc[2][2] += a2 * b2; acc[2][3] += a2 * b3;
      acc[3][0] += a3 * b0; acc[3][1] += a3 * b1; acc[3][2] += a3 * b2; acc[3][3] += a3 * b3;
    }
    __syncthreads();
  }

#pragma unroll
  for (int i = 0; i < 4; ++i) {
    int gr = m0 + ty + i * 16;
    if (gr >= M_) continue;
#pragma unroll
    for (int j = 0; j < 4; ++j) {
      int c = n0 + tx + j * 16;
      out[(size_t)gr * DIM_ + c] = acc[i][j] + bias[c];
    }
  }
}

// ---------------------------------------------------------------------------
extern "C" void kernel_launch(void* const* d_in, const int* in_sizes, int n_in,
                              void* d_out, int out_size, void* d_ws, size_t ws_size,
                              hipStream_t stream) {
  (void)in_sizes; (void)n_in; (void)out_size; (void)ws_size;
  const float* x    = (const float*)d_in[0];
  const float* wqkv = (const float*)d_in[1];
  const float* wout = (const float*)d_in[2];
  const float* bout = (const float*)d_in[3];
  float* ws = (float*)d_ws;
  float* qw = ws + QOFF;
  float* kw = ws + KOFF;
  float* vw = ws + VOFF;
  float* attn = ws + AOFF;
  float* out = (float*)d_out;

  dim3 g1((M_ + 63) / 64, NQKV_ / 64);   // 393 x 24
  qkv_gemm_kernel<<<g1, 256, 0, stream>>>(x, wqkv, ws);

  cls_attn_kernel<<<BH_, 256, 0, stream>>>(qw, kw, vw, attn);

  frame_attn_kernel<<<BH_ * F_, 256, 0, stream>>>(qw, kw, vw, attn);

  dim3 g2((M_ + 63) / 64, DIM_ / 64);    // 393 x 8
  out_gemm_kernel<<<g2, 256, 0, stream>>>(attn, wout, bout, out);
}

// Round 2
// 722.682 us; speedup vs baseline: 2.2408x; 2.2408x over previous
//
#include <hip/hip_runtime.h>
#include <hip/hip_bf16.h>

// Problem constants
#define B_    8
#define F_    16
#define NP_   196
#define SEQ_  3137        // 1 + F_*NP_
#define H_    8
#define DH_   64
#define BH_   64          // B_*H_
#define M_    25096       // B_*SEQ_
#define MPAD_ 25216       // padded to 128-multiple (197*128)
#define DIM_  512
#define NQKV_ 1536

typedef _Float16 half8_t __attribute__((ext_vector_type(8)));
typedef float f32x4 __attribute__((ext_vector_type(4)));

// workspace byte offsets
#define XH_OFF     ((size_t)0)                    // [MPAD_][512] f16   25,821,184
#define WQKVT_OFF  ((size_t)25821184)             // [1536][512] f16     1,572,864
#define WOUTT_OFF  ((size_t)27394048)             // [512][512]  f16       524,288
#define QH_OFF     ((size_t)27918336)             // [64][3137][64] f16 25,698,304
#define KH_OFF     ((size_t)53616640)
#define VH_OFF     ((size_t)79314944)
#define ATTNH_OFF  ((size_t)105013248)            // [MPAD_][512] f16   25,821,184

__device__ __forceinline__ void load_lds16(const _Float16* g, _Float16* l) {
  __builtin_amdgcn_global_load_lds(
      (const __attribute__((address_space(1))) void*)g,
      (__attribute__((address_space(3))) void*)l, 16, 0, 0);
}

// ---------------------------------------------------------------------------
// conversion kernels
// ---------------------------------------------------------------------------
__global__ __launch_bounds__(256) void convert_x_kernel(
    const float* __restrict__ x, _Float16* __restrict__ xh) {
  const size_t n8 = (size_t)M_ * DIM_ / 8;
  for (size_t i = (size_t)blockIdx.x * blockDim.x + threadIdx.x; i < n8;
       i += (size_t)gridDim.x * blockDim.x) {
    float4 a = ((const float4*)x)[2 * i];
    float4 b = ((const float4*)x)[2 * i + 1];
    half8_t h;
    h[0] = (_Float16)a.x; h[1] = (_Float16)a.y; h[2] = (_Float16)a.z; h[3] = (_Float16)a.w;
    h[4] = (_Float16)b.x; h[5] = (_Float16)b.y; h[6] = (_Float16)b.z; h[7] = (_Float16)b.w;
    ((half8_t*)xh)[i] = h;
  }
}

// in [R][C] fp32 -> out [C][R] fp16  (R,C multiples of 32)
__global__ __launch_bounds__(256) void transpose_conv_kernel(
    const float* __restrict__ in, _Float16* __restrict__ out, int R, int C) {
  __shared__ float tile[32][33];
  const int r0 = blockIdx.x * 32, c0 = blockIdx.y * 32;
  const int lr = threadIdx.x >> 5, lc = threadIdx.x & 31;
#pragma unroll
  for (int p = 0; p < 4; ++p) {
    int r = p * 8 + lr;
    tile[r][lc] = in[(size_t)(r0 + r) * C + c0 + lc];
  }
  __syncthreads();
#pragma unroll
  for (int p = 0; p < 4; ++p) {
    int rr = p * 8 + lr;
    out[(size_t)(c0 + rr) * R + r0 + lc] = (_Float16)tile[lc][rr];
  }
}

// ---------------------------------------------------------------------------
// shared f16 MFMA mainloop: 128x128 tile, BK=32, 256 threads (4 waves 2x2),
// A [*][512] row-major f16, B^T [*][512] row-major f16. acc[m][n] per wave.
// ---------------------------------------------------------------------------
__device__ __forceinline__ void gemm_mainloop_f16(
    const _Float16* __restrict__ A, const _Float16* __restrict__ Bt,
    int m0, int n0, _Float16* As, _Float16* Bs, f32x4 acc[4][4]) {
  const int tid = threadIdx.x;
  const int w = tid >> 6, lane = tid & 63;
  const int wr = w >> 1, wc = w & 1;
  const int lrow = lane & 15, lk = (lane >> 4) * 8;

  // staging geometry: chunk = 1024B = 16 rows of 32 f16; wave w does chunks 2w,2w+1
  const int c0 = 2 * w, c1 = 2 * w + 1;
  const int sr0 = c0 * 16 + (lane >> 2), sr1 = c1 * 16 + (lane >> 2);
  const int sk = (lane & 3) * 8;

  for (int k0 = 0; k0 < DIM_; k0 += 32) {
    load_lds16(A + (size_t)(m0 + sr0) * DIM_ + k0 + sk, As + c0 * 512);
    load_lds16(A + (size_t)(m0 + sr1) * DIM_ + k0 + sk, As + c1 * 512);
    load_lds16(Bt + (size_t)(n0 + sr0) * DIM_ + k0 + sk, Bs + c0 * 512);
    load_lds16(Bt + (size_t)(n0 + sr1) * DIM_ + k0 + sk, Bs + c1 * 512);
    __syncthreads();

    half8_t a[4], b[4];
#pragma unroll
    for (int m = 0; m < 4; ++m)
      a[m] = *(const half8_t*)(As + (wr * 64 + m * 16 + lrow) * 32 + lk);
#pragma unroll
    for (int n = 0; n < 4; ++n)
      b[n] = *(const half8_t*)(Bs + (wc * 64 + n * 16 + lrow) * 32 + lk);
#pragma unroll
    for (int m = 0; m < 4; ++m)
#pragma unroll
      for (int n = 0; n < 4; ++n)
        acc[m][n] = __builtin_amdgcn_mfma_f32_16x16x32_f16(a[m], b[n], acc[m][n], 0, 0, 0);
    __syncthreads();
  }
}

// ---------------------------------------------------------------------------
// K1: qkv = xh @ WqkvT^T, scatter into qh/kh/vh [bh][t][64] f16, q scaled.
// ---------------------------------------------------------------------------
__global__ __launch_bounds__(256) void qkv_gemm_kernel(
    const _Float16* __restrict__ xh, const _Float16* __restrict__ wqkvT,
    _Float16* __restrict__ qh, _Float16* __restrict__ kh, _Float16* __restrict__ vh) {
  __shared__ _Float16 As[128 * 32];
  __shared__ _Float16 Bs[128 * 32];
  const int m0 = blockIdx.x * 128, n0 = blockIdx.y * 128;
  f32x4 acc[4][4];
#pragma unroll
  for (int m = 0; m < 4; ++m)
#pragma unroll
    for (int n = 0; n < 4; ++n) acc[m][n] = (f32x4)0.f;

  gemm_mainloop_f16(xh, wqkvT, m0, n0, As, Bs, acc);

  const int tid = threadIdx.x;
  const int w = tid >> 6, lane = tid & 63;
  const int wr = w >> 1, wc = w & 1;
#pragma unroll
  for (int n = 0; n < 4; ++n) {
    const int gcb = n0 + wc * 64 + n * 16;      // wave-uniform column base
    const int which = gcb >> 9;
    const int h = (gcb >> 6) & 7;
    const int dbase = (gcb & 63) + (lane & 15);
    const float scale = (which == 0) ? 0.125f : 1.0f;
    _Float16* dst = (which == 0) ? qh : (which == 1) ? kh : vh;
#pragma unroll
    for (int m = 0; m < 4; ++m)
#pragma unroll
      for (int j = 0; j < 4; ++j) {
        int grow = m0 + wr * 64 + m * 16 + (lane >> 4) * 4 + j;
        if (grow < M_) {
          int b = grow / SEQ_;
          int t = grow - b * SEQ_;
          dst[((size_t)(b * H_ + h) * SEQ_ + t) * DH_ + dbase] =
              (_Float16)(acc[m][n][j] * scale);
        }
      }
  }
}

// ---------------------------------------------------------------------------
// K2: CLS attention (fp16 in, fp32 math). One block per (b,h).
// ---------------------------------------------------------------------------
__global__ __launch_bounds__(256) void cls_attn_kernel(
    const _Float16* __restrict__ qh, const _Float16* __restrict__ kh,
    const _Float16* __restrict__ vh, _Float16* __restrict__ attnh) {
  const int bh = blockIdx.x;
  const int b = bh >> 3, h = bh & 7;
  const int tid = threadIdx.x;
  __shared__ float qs[64];
  __shared__ float s[SEQ_];
  __shared__ float red[256];

  if (tid < 64) qs[tid] = (float)qh[(size_t)bh * SEQ_ * DH_ + tid];
  __syncthreads();

  float lmax = -1e30f;
  for (int j = tid; j < SEQ_; j += 256) {
    const half8_t* kr = (const half8_t*)(kh + ((size_t)bh * SEQ_ + j) * DH_);
    float sc = 0.f;
#pragma unroll
    for (int i = 0; i < 8; ++i) {
      half8_t kk = kr[i];
#pragma unroll
      for (int u = 0; u < 8; ++u) sc += qs[8 * i + u] * (float)kk[u];
    }
    s[j] = sc;
    lmax = fmaxf(lmax, sc);
  }
  red[tid] = lmax; __syncthreads();
  for (int st = 128; st > 0; st >>= 1) {
    if (tid < st) red[tid] = fmaxf(red[tid], red[tid + st]);
    __syncthreads();
  }
  float m = red[0]; __syncthreads();

  float lsum = 0.f;
  for (int j = tid; j < SEQ_; j += 256) {
    float p = __expf(s[j] - m);
    s[j] = p;
    lsum += p;
  }
  red[tid] = lsum; __syncthreads();
  for (int st = 128; st > 0; st >>= 1) {
    if (tid < st) red[tid] += red[tid + st];
    __syncthreads();
  }
  float l = red[0]; __syncthreads();

  const int d = tid & 63, c = tid >> 6;
  float a = 0.f;
  for (int j = c; j < SEQ_; j += 4)
    a += s[j] * (float)vh[((size_t)bh * SEQ_ + j) * DH_ + d];
  red[tid] = a; __syncthreads();
  if (tid < 64) {
    float o = (red[tid] + red[64 + tid] + red[128 + tid] + red[192 + tid]) / l;
    attnh[(size_t)(b * SEQ_) * DIM_ + h * DH_ + tid] = (_Float16)o;
  }
}

// ---------------------------------------------------------------------------
// K3: frame attention (fp16 in, fp32 math, fp16 out).
// ---------------------------------------------------------------------------
__global__ __launch_bounds__(256) void frame_attn_kernel(
    const _Float16* __restrict__ qh, const _Float16* __restrict__ kh,
    const _Float16* __restrict__ vh, _Float16* __restrict__ attnh) {
  const int bx = blockIdx.x;
  const int bh = bx >> 4, fi = bx & 15;
  const int b = bh >> 3, h = bh & 7;
  const int tid = threadIdx.x;
  const bool active = tid < NP_;
  const int q = active ? tid : 0;
  const int tok = 1 + fi * NP_ + q;
  const int NK = NP_ + 1;  // 197

  __shared__ float Ks[64][64];
  __shared__ float Vs[64][64];

  float4 qv[16];
  {
    const half8_t* qp = (const half8_t*)(qh + ((size_t)bh * SEQ_ + tok) * DH_);
#pragma unroll
    for (int i = 0; i < 8; ++i) {
      half8_t hq = qp[i];
      qv[2 * i].x = (float)hq[0]; qv[2 * i].y = (float)hq[1];
      qv[2 * i].z = (float)hq[2]; qv[2 * i].w = (float)hq[3];
      qv[2 * i + 1].x = (float)hq[4]; qv[2 * i + 1].y = (float)hq[5];
      qv[2 * i + 1].z = (float)hq[6]; qv[2 * i + 1].w = (float)hq[7];
    }
  }
  float acc[64];
#pragma unroll
  for (int d = 0; d < 64; ++d) acc[d] = 0.f;
  float m = -1e30f, l = 0.f;

  for (int j0 = 0; j0 < NK; j0 += 64) {
    const int nk = min(64, NK - j0);
    for (int idx = tid; idx < nk * 8; idx += 256) {
      int jj = idx >> 3, part = idx & 7;
      int jg = j0 + jj;
      size_t row = (jg == 0) ? ((size_t)bh * SEQ_)
                             : ((size_t)bh * SEQ_ + 1 + fi * NP_ + jg - 1);
      half8_t hk = ((const half8_t*)(kh + row * DH_))[part];
      half8_t hv = ((const half8_t*)(vh + row * DH_))[part];
#pragma unroll
      for (int u = 0; u < 8; ++u) {
        Ks[jj][part * 8 + u] = (float)hk[u];
        Vs[jj][part * 8 + u] = (float)hv[u];
      }
    }
    __syncthreads();

#pragma unroll
    for (int sub = 0; sub < 4; ++sub) {
      if (j0 + sub * 16 < NK) {
        float s[16];
        float tmax = -1e30f;
#pragma unroll
        for (int u = 0; u < 16; ++u) {
          int jj = sub * 16 + u;
          const float4* krow = (const float4*)Ks[jj];
          float sc = 0.f;
#pragma unroll
          for (int i = 0; i < 16; ++i) {
            float4 kk = krow[i];
            sc += qv[i].x * kk.x + qv[i].y * kk.y + qv[i].z * kk.z + qv[i].w * kk.w;
          }
          sc = (j0 + jj < NK) ? sc : -1e30f;
          s[u] = sc;
          tmax = fmaxf(tmax, sc);
        }
        float mn = fmaxf(m, tmax);
        float corr = __expf(m - mn);
        l *= corr;
#pragma unroll
        for (int d = 0; d < 64; ++d) acc[d] *= corr;
#pragma unroll
        for (int u = 0; u < 16; ++u) {
          int jj = sub * 16 + u;
          float p = __expf(s[u] - mn);
          l += p;
          const float4* vrow = (const float4*)Vs[jj];
#pragma unroll
          for (int i = 0; i < 16; ++i) {
            float4 vv = vrow[i];
            acc[4 * i + 0] += p * vv.x;
            acc[4 * i + 1] += p * vv.y;
            acc[4 * i + 2] += p * vv.z;
            acc[4 * i + 3] += p * vv.w;
          }
        }
        m = mn;
      }
    }
    __syncthreads();
  }

  if (active) {
    float inv = 1.f / l;
    _Float16* op = attnh + ((size_t)(b * SEQ_) + tok) * DIM_ + h * DH_;
#pragma unroll
    for (int d = 0; d < 64; ++d) op[d] = (_Float16)(acc[d] * inv);
  }
}

// ---------------------------------------------------------------------------
// K4: out = attnh @ WoutT^T + bout (fp32 out).
// ---------------------------------------------------------------------------
__global__ __launch_bounds__(256) void out_gemm_kernel(
    const _Float16* __restrict__ attnh, const _Float16* __restrict__ woutT,
    const float* __restrict__ bias, float* __restrict__ out) {
  __shared__ _Float16 As[128 * 32];
  __shared__ _Float16 Bs[128 * 32];
  const int m0 = blockIdx.x * 128, n0 = blockIdx.y * 128;
  f32x4 acc[4][4];
#pragma unroll
  for (int m = 0; m < 4; ++m)
#pragma unroll
    for (int n = 0; n < 4; ++n) acc[m][n] = (f32x4)0.f;

  gemm_mainloop_f16(attnh, woutT, m0, n0, As, Bs, acc);

  const int tid = threadIdx.x;
  const int w = tid >> 6, lane = tid & 63;
  const int wr = w >> 1, wc = w & 1;
#pragma unroll
  for (int n = 0; n < 4; ++n) {
    const int gcol = n0 + wc * 64 + n * 16 + (lane & 15);
    const float bv = bias[gcol];
#pragma unroll
    for (int m = 0; m < 4; ++m)
#pragma unroll
      for (int j = 0; j < 4; ++j) {
        int grow = m0 + wr * 64 + m * 16 + (lane >> 4) * 4 + j;
        if (grow < M_) out[(size_t)grow * DIM_ + gcol] = acc[m][n][j] + bv;
      }
  }
}

// ---------------------------------------------------------------------------
extern "C" void kernel_launch(void* const* d_in, const int* in_sizes, int n_in,
                              void* d_out, int out_size, void* d_ws, size_t ws_size,
                              hipStream_t stream) {
  (void)in_sizes; (void)n_in; (void)out_size; (void)ws_size;
  const float* x    = (const float*)d_in[0];
  const float* wqkv = (const float*)d_in[1];
  const float* wout = (const float*)d_in[2];
  const float* bout = (const float*)d_in[3];
  char* ws = (char*)d_ws;
  _Float16* xh    = (_Float16*)(ws + XH_OFF);
  _Float16* wqkvT = (_Float16*)(ws + WQKVT_OFF);
  _Float16* woutT = (_Float16*)(ws + WOUTT_OFF);
  _Float16* qh    = (_Float16*)(ws + QH_OFF);
  _Float16* kh    = (_Float16*)(ws + KH_OFF);
  _Float16* vh    = (_Float16*)(ws + VH_OFF);
  _Float16* attnh = (_Float16*)(ws + ATTNH_OFF);
  float* out = (float*)d_out;

  convert_x_kernel<<<2048, 256, 0, stream>>>(x, xh);
  {
    dim3 g(DIM_ / 32, NQKV_ / 32);  // R=512, C=1536
    transpose_conv_kernel<<<g, 256, 0, stream>>>(wqkv, wqkvT, DIM_, NQKV_);
  }
  {
    dim3 g(DIM_ / 32, DIM_ / 32);
    transpose_conv_kernel<<<g, 256, 0, stream>>>(wout, woutT, DIM_, DIM_);
  }

  dim3 g1(MPAD_ / 128, NQKV_ / 128);  // 197 x 12
  qkv_gemm_kernel<<<g1, 256, 0, stream>>>(xh, wqkvT, qh, kh, vh);

  cls_attn_kernel<<<BH_, 256, 0, stream>>>(qh, kh, vh, attnh);
  frame_attn_kernel<<<BH_ * F_, 256, 0, stream>>>(qh, kh, vh, attnh);

  dim3 g2(MPAD_ / 128, DIM_ / 128);   // 197 x 4
  out_gemm_kernel<<<g2, 256, 0, stream>>>(attnh, woutT, bout, out);
}

// Round 3
// 271.148 us; speedup vs baseline: 5.9724x; 2.6653x over previous
//
#include <hip/hip_runtime.h>
#include <hip/hip_bf16.h>

// Problem constants
#define B_    8
#define F_    16
#define NP_   196
#define SEQ_  3137        // 1 + F_*NP_
#define H_    8
#define DH_   64
#define BH_   64          // B_*H_
#define M_    25096       // B_*SEQ_
#define MPAD_ 25216       // padded to 128-multiple (197*128)
#define DIM_  512
#define NQKV_ 1536

typedef _Float16 half8_t __attribute__((ext_vector_type(8)));
typedef _Float16 half4_t __attribute__((ext_vector_type(4)));
typedef float f32x4 __attribute__((ext_vector_type(4)));

// workspace byte offsets
#define XH_OFF     ((size_t)0)                    // [MPAD_][512] f16   25,821,184
#define WQKVT_OFF  ((size_t)25821184)             // [1536][512] f16     1,572,864
#define WOUTT_OFF  ((size_t)27394048)             // [512][512]  f16       524,288
#define QH_OFF     ((size_t)27918336)             // [64][3137][64] f16 25,698,304
#define KH_OFF     ((size_t)53616640)
#define VH_OFF     ((size_t)79314944)
#define ATTNH_OFF  ((size_t)105013248)            // [MPAD_][512] f16   25,821,184

__device__ __forceinline__ void load_lds16(const _Float16* g, _Float16* l) {
  __builtin_amdgcn_global_load_lds(
      (const __attribute__((address_space(1))) void*)g,
      (__attribute__((address_space(3))) void*)l, 16, 0, 0);
}

// ---------------------------------------------------------------------------
// conversion kernels
// ---------------------------------------------------------------------------
__global__ __launch_bounds__(256) void convert_x_kernel(
    const float* __restrict__ x, _Float16* __restrict__ xh) {
  const size_t n8 = (size_t)M_ * DIM_ / 8;
  for (size_t i = (size_t)blockIdx.x * blockDim.x + threadIdx.x; i < n8;
       i += (size_t)gridDim.x * blockDim.x) {
    float4 a = ((const float4*)x)[2 * i];
    float4 b = ((const float4*)x)[2 * i + 1];
    half8_t h;
    h[0] = (_Float16)a.x; h[1] = (_Float16)a.y; h[2] = (_Float16)a.z; h[3] = (_Float16)a.w;
    h[4] = (_Float16)b.x; h[5] = (_Float16)b.y; h[6] = (_Float16)b.z; h[7] = (_Float16)b.w;
    ((half8_t*)xh)[i] = h;
  }
}

// in [R][C] fp32 -> out [C][R] fp16  (R,C multiples of 32)
__global__ __launch_bounds__(256) void transpose_conv_kernel(
    const float* __restrict__ in, _Float16* __restrict__ out, int R, int C) {
  __shared__ float tile[32][33];
  const int r0 = blockIdx.x * 32, c0 = blockIdx.y * 32;
  const int lr = threadIdx.x >> 5, lc = threadIdx.x & 31;
#pragma unroll
  for (int p = 0; p < 4; ++p) {
    int r = p * 8 + lr;
    tile[r][lc] = in[(size_t)(r0 + r) * C + c0 + lc];
  }
  __syncthreads();
#pragma unroll
  for (int p = 0; p < 4; ++p) {
    int rr = p * 8 + lr;
    out[(size_t)(c0 + rr) * R + r0 + lc] = (_Float16)tile[lc][rr];
  }
}

// ---------------------------------------------------------------------------
// shared f16 MFMA mainloop: 128x128 tile, BK=32, 256 threads (4 waves 2x2)
// ---------------------------------------------------------------------------
__device__ __forceinline__ void gemm_mainloop_f16(
    const _Float16* __restrict__ A, const _Float16* __restrict__ Bt,
    int m0, int n0, _Float16* As, _Float16* Bs, f32x4 acc[4][4]) {
  const int tid = threadIdx.x;
  const int w = tid >> 6, lane = tid & 63;
  const int wr = w >> 1, wc = w & 1;
  const int lrow = lane & 15, lk = (lane >> 4) * 8;

  const int c0 = 2 * w, c1 = 2 * w + 1;
  const int sr0 = c0 * 16 + (lane >> 2), sr1 = c1 * 16 + (lane >> 2);
  const int sk = (lane & 3) * 8;

  for (int k0 = 0; k0 < DIM_; k0 += 32) {
    load_lds16(A + (size_t)(m0 + sr0) * DIM_ + k0 + sk, As + c0 * 512);
    load_lds16(A + (size_t)(m0 + sr1) * DIM_ + k0 + sk, As + c1 * 512);
    load_lds16(Bt + (size_t)(n0 + sr0) * DIM_ + k0 + sk, Bs + c0 * 512);
    load_lds16(Bt + (size_t)(n0 + sr1) * DIM_ + k0 + sk, Bs + c1 * 512);
    __syncthreads();

    half8_t a[4], b[4];
#pragma unroll
    for (int m = 0; m < 4; ++m)
      a[m] = *(const half8_t*)(As + (wr * 64 + m * 16 + lrow) * 32 + lk);
#pragma unroll
    for (int n = 0; n < 4; ++n)
      b[n] = *(const half8_t*)(Bs + (wc * 64 + n * 16 + lrow) * 32 + lk);
#pragma unroll
    for (int m = 0; m < 4; ++m)
#pragma unroll
      for (int n = 0; n < 4; ++n)
        acc[m][n] = __builtin_amdgcn_mfma_f32_16x16x32_f16(a[m], b[n], acc[m][n], 0, 0, 0);
    __syncthreads();
  }
}

// ---------------------------------------------------------------------------
// K1: qkv = xh @ WqkvT^T, scatter into qh/kh/vh [bh][t][64] f16, q scaled.
// ---------------------------------------------------------------------------
__global__ __launch_bounds__(256) void qkv_gemm_kernel(
    const _Float16* __restrict__ xh, const _Float16* __restrict__ wqkvT,
    _Float16* __restrict__ qh, _Float16* __restrict__ kh, _Float16* __restrict__ vh) {
  __shared__ _Float16 As[128 * 32];
  __shared__ _Float16 Bs[128 * 32];
  const int m0 = blockIdx.x * 128, n0 = blockIdx.y * 128;
  f32x4 acc[4][4];
#pragma unroll
  for (int m = 0; m < 4; ++m)
#pragma unroll
    for (int n = 0; n < 4; ++n) acc[m][n] = (f32x4)0.f;

  gemm_mainloop_f16(xh, wqkvT, m0, n0, As, Bs, acc);

  const int tid = threadIdx.x;
  const int w = tid >> 6, lane = tid & 63;
  const int wr = w >> 1, wc = w & 1;
#pragma unroll
  for (int n = 0; n < 4; ++n) {
    const int gcb = n0 + wc * 64 + n * 16;
    const int which = gcb >> 9;
    const int h = (gcb >> 6) & 7;
    const int dbase = (gcb & 63) + (lane & 15);
    const float scale = (which == 0) ? 0.125f : 1.0f;
    _Float16* dst = (which == 0) ? qh : (which == 1) ? kh : vh;
#pragma unroll
    for (int m = 0; m < 4; ++m)
#pragma unroll
      for (int j = 0; j < 4; ++j) {
        int grow = m0 + wr * 64 + m * 16 + (lane >> 4) * 4 + j;
        if (grow < M_) {
          int b = grow / SEQ_;
          int t = grow - b * SEQ_;
          dst[((size_t)(b * H_ + h) * SEQ_ + t) * DH_ + dbase] =
              (_Float16)(acc[m][n][j] * scale);
        }
      }
  }
}

// ---------------------------------------------------------------------------
// K2: CLS attention (fp16 in, fp32 math). One block per (b,h), 1024 threads.
// ---------------------------------------------------------------------------
__global__ __launch_bounds__(1024) void cls_attn_kernel(
    const _Float16* __restrict__ qh, const _Float16* __restrict__ kh,
    const _Float16* __restrict__ vh, _Float16* __restrict__ attnh) {
  const int bh = blockIdx.x;
  const int b = bh >> 3, h = bh & 7;
  const int tid = threadIdx.x;
  __shared__ float qs[64];
  __shared__ float s[SEQ_];
  __shared__ float red[1024];

  if (tid < 64) qs[tid] = (float)qh[(size_t)bh * SEQ_ * DH_ + tid];
  __syncthreads();

  float lmax = -1e30f;
  for (int j = tid; j < SEQ_; j += 1024) {
    const half8_t* kr = (const half8_t*)(kh + ((size_t)bh * SEQ_ + j) * DH_);
    float sc = 0.f;
#pragma unroll
    for (int i = 0; i < 8; ++i) {
      half8_t kk = kr[i];
#pragma unroll
      for (int u = 0; u < 8; ++u) sc += qs[8 * i + u] * (float)kk[u];
    }
    s[j] = sc;
    lmax = fmaxf(lmax, sc);
  }
  red[tid] = lmax; __syncthreads();
  for (int st = 512; st > 0; st >>= 1) {
    if (tid < st) red[tid] = fmaxf(red[tid], red[tid + st]);
    __syncthreads();
  }
  float m = red[0]; __syncthreads();

  float lsum = 0.f;
  for (int j = tid; j < SEQ_; j += 1024) {
    float p = __expf(s[j] - m);
    s[j] = p;
    lsum += p;
  }
  red[tid] = lsum; __syncthreads();
  for (int st = 512; st > 0; st >>= 1) {
    if (tid < st) red[tid] += red[tid + st];
    __syncthreads();
  }
  float l = red[0]; __syncthreads();

  const int d = tid & 63, c = tid >> 6;  // c in 0..15
  float a = 0.f;
  for (int j = c; j < SEQ_; j += 16)
    a += s[j] * (float)vh[((size_t)bh * SEQ_ + j) * DH_ + d];
  red[tid] = a; __syncthreads();
  if (tid < 64) {
    float o = 0.f;
#pragma unroll
    for (int i = 0; i < 16; ++i) o += red[i * 64 + tid];
    attnh[(size_t)(b * SEQ_) * DIM_ + h * DH_ + tid] = (_Float16)(o / l);
  }
}

// ---------------------------------------------------------------------------
// K3: frame attention, MFMA. One block per (bh, frame), 4 waves.
// Swapped QK^T (S^T = K·Q, col=q=lane&15), per-wave softmax in registers,
// P via per-wave LDS round-trip, V^T staged in LDS for PV B-frags.
// ---------------------------------------------------------------------------
__global__ __launch_bounds__(256) void frame_attn_kernel(
    const _Float16* __restrict__ qh, const _Float16* __restrict__ kh,
    const _Float16* __restrict__ vh, _Float16* __restrict__ attnh) {
  const int bx = blockIdx.x;
  const int bh = bx >> 4, fi = bx & 15;
  const int b = bh >> 3, h = bh & 7;
  const int tid = threadIdx.x;
  const int w = tid >> 6, lane = tid & 63;
  const int g = lane >> 4, lc = lane & 15;

  __shared__ _Float16 VT[64 * 232];      // V^T [d][key], cols 197..231 zero
  __shared__ _Float16 Pb[4][16 * 232];   // per-wave P [q][key]
  _Float16* Pw = Pb[w];

  const size_t base = (size_t)bh * SEQ_ * DH_;

  // stage V^T (transpose-scatter), valid keys 0..196
  for (int item = tid; item < 197 * 8; item += 256) {
    int c8 = item / 197;
    int key = item - c8 * 197;
    int rowtok = (key == 0) ? 0 : fi * NP_ + key;  // token index within bh
    half8_t hv = *(const half8_t*)(vh + base + (size_t)rowtok * DH_ + c8 * 8);
#pragma unroll
    for (int u = 0; u < 8; ++u) VT[(c8 * 8 + u) * 232 + key] = hv[u];
  }
  // zero VT cols 197..231
  for (int idx = tid; idx < 64 * 35; idx += 256) {
    int d = idx / 35;
    VT[d * 232 + 197 + (idx - d * 35)] = (_Float16)0.f;
  }
  // zero P cols 208..223 (wave-private, read by PV chunk 6)
#pragma unroll
  for (int z = 0; z < 4; ++z) {
    int idx = z * 64 + lane;
    Pw[(idx >> 4) * 232 + 208 + (idx & 15)] = (_Float16)0.f;
  }
  __syncthreads();

  const f32x4 zero4 = (f32x4)0.f;

  for (int qt = w; qt < 13; qt += 4) {
    // Q B-frags (col=q=lc), direct from global, clamped
    int qq = qt * 16 + lc;
    int qtok = 1 + fi * NP_ + min(qq, NP_ - 1);
    const _Float16* qp = qh + base + (size_t)qtok * DH_ + g * 8;
    half8_t qb0 = *(const half8_t*)(qp);
    half8_t qb1 = *(const half8_t*)(qp + 32);

    // S^T: 13 key-tiles; A-frag = K rows (row=key=lc within tile)
    f32x4 st[13];
#pragma unroll
    for (int t = 0; t < 13; ++t) {
      int key = t * 16 + lc;
      int rowtok = (key == 0) ? 0 : fi * NP_ + min(key, NP_);  // clamp >=197 -> 196
      const _Float16* kp = kh + base + (size_t)rowtok * DH_ + g * 8;
      half8_t ka0 = *(const half8_t*)(kp);
      half8_t ka1 = *(const half8_t*)(kp + 32);
      st[t] = __builtin_amdgcn_mfma_f32_16x16x32_f16(ka0, qb0, zero4, 0, 0, 0);
      st[t] = __builtin_amdgcn_mfma_f32_16x16x32_f16(ka1, qb1, st[t], 0, 0, 0);
    }

    // mask + softmax. Per lane: q = lc, keys = t*16 + g*4 + j
    float mx = -1e30f;
#pragma unroll
    for (int t = 0; t < 13; ++t)
#pragma unroll
      for (int j = 0; j < 4; ++j) {
        int key = t * 16 + g * 4 + j;
        if (key >= 197) st[t][j] = -1e30f;
        mx = fmaxf(mx, st[t][j]);
      }
    mx = fmaxf(mx, __shfl_xor(mx, 16));
    mx = fmaxf(mx, __shfl_xor(mx, 32));
    float l = 0.f;
#pragma unroll
    for (int t = 0; t < 13; ++t)
#pragma unroll
      for (int j = 0; j < 4; ++j) {
        float p = __expf(st[t][j] - mx);
        st[t][j] = p;
        l += p;
      }
    l += __shfl_xor(l, 16);
    l += __shfl_xor(l, 32);
    const float inv = 1.f / l;

    // store P = p/l as f16 rows [q=lc][key]
#pragma unroll
    for (int t = 0; t < 13; ++t) {
      half4_t hp;
#pragma unroll
      for (int j = 0; j < 4; ++j) hp[j] = (_Float16)(st[t][j] * inv);
      *(half4_t*)(Pw + lc * 232 + t * 16 + g * 4) = hp;
    }

    // PV: O[q][d] = P[q][k] V[k][d]; A-frag from Pw, B-frag from VT
    f32x4 o[4];
#pragma unroll
    for (int dt = 0; dt < 4; ++dt) o[dt] = zero4;
#pragma unroll
    for (int c = 0; c < 7; ++c) {
      half8_t pa = *(const half8_t*)(Pw + lc * 232 + c * 32 + g * 8);
#pragma unroll
      for (int dt = 0; dt < 4; ++dt) {
        half8_t vb = *(const half8_t*)(VT + (dt * 16 + lc) * 232 + c * 32 + g * 8);
        o[dt] = __builtin_amdgcn_mfma_f32_16x16x32_f16(pa, vb, o[dt], 0, 0, 0);
      }
    }

    // write O tile: row=q=g*4+j, col=d=dt*16+lc
#pragma unroll
    for (int dt = 0; dt < 4; ++dt)
#pragma unroll
      for (int j = 0; j < 4; ++j) {
        int q = qt * 16 + g * 4 + j;
        if (q < NP_) {
          int tok = 1 + fi * NP_ + q;
          attnh[((size_t)(b * SEQ_) + tok) * DIM_ + h * DH_ + dt * 16 + lc] =
              (_Float16)o[dt][j];
        }
      }
  }
}

// ---------------------------------------------------------------------------
// K4: out = attnh @ WoutT^T + bout (fp32 out).
// ---------------------------------------------------------------------------
__global__ __launch_bounds__(256) void out_gemm_kernel(
    const _Float16* __restrict__ attnh, const _Float16* __restrict__ woutT,
    const float* __restrict__ bias, float* __restrict__ out) {
  __shared__ _Float16 As[128 * 32];
  __shared__ _Float16 Bs[128 * 32];
  const int m0 = blockIdx.x * 128, n0 = blockIdx.y * 128;
  f32x4 acc[4][4];
#pragma unroll
  for (int m = 0; m < 4; ++m)
#pragma unroll
    for (int n = 0; n < 4; ++n) acc[m][n] = (f32x4)0.f;

  gemm_mainloop_f16(attnh, woutT, m0, n0, As, Bs, acc);

  const int tid = threadIdx.x;
  const int w = tid >> 6, lane = tid & 63;
  const int wr = w >> 1, wc = w & 1;
#pragma unroll
  for (int n = 0; n < 4; ++n) {
    const int gcol = n0 + wc * 64 + n * 16 + (lane & 15);
    const float bv = bias[gcol];
#pragma unroll
    for (int m = 0; m < 4; ++m)
#pragma unroll
      for (int j = 0; j < 4; ++j) {
        int grow = m0 + wr * 64 + m * 16 + (lane >> 4) * 4 + j;
        if (grow < M_) out[(size_t)grow * DIM_ + gcol] = acc[m][n][j] + bv;
      }
  }
}

// ---------------------------------------------------------------------------
extern "C" void kernel_launch(void* const* d_in, const int* in_sizes, int n_in,
                              void* d_out, int out_size, void* d_ws, size_t ws_size,
                              hipStream_t stream) {
  (void)in_sizes; (void)n_in; (void)out_size; (void)ws_size;
  const float* x    = (const float*)d_in[0];
  const float* wqkv = (const float*)d_in[1];
  const float* wout = (const float*)d_in[2];
  const float* bout = (const float*)d_in[3];
  char* ws = (char*)d_ws;
  _Float16* xh    = (_Float16*)(ws + XH_OFF);
  _Float16* wqkvT = (_Float16*)(ws + WQKVT_OFF);
  _Float16* woutT = (_Float16*)(ws + WOUTT_OFF);
  _Float16* qh    = (_Float16*)(ws + QH_OFF);
  _Float16* kh    = (_Float16*)(ws + KH_OFF);
  _Float16* vh    = (_Float16*)(ws + VH_OFF);
  _Float16* attnh = (_Float16*)(ws + ATTNH_OFF);
  float* out = (float*)d_out;

  convert_x_kernel<<<2048, 256, 0, stream>>>(x, xh);
  {
    dim3 g(DIM_ / 32, NQKV_ / 32);
    transpose_conv_kernel<<<g, 256, 0, stream>>>(wqkv, wqkvT, DIM_, NQKV_);
  }
  {
    dim3 g(DIM_ / 32, DIM_ / 32);
    transpose_conv_kernel<<<g, 256, 0, stream>>>(wout, woutT, DIM_, DIM_);
  }

  dim3 g1(MPAD_ / 128, NQKV_ / 128);  // 197 x 12
  qkv_gemm_kernel<<<g1, 256, 0, stream>>>(xh, wqkvT, qh, kh, vh);

  cls_attn_kernel<<<BH_, 1024, 0, stream>>>(qh, kh, vh, attnh);
  frame_attn_kernel<<<BH_ * F_, 256, 0, stream>>>(qh, kh, vh, attnh);

  dim3 g2(MPAD_ / 128, DIM_ / 128);   // 197 x 4
  out_gemm_kernel<<<g2, 256, 0, stream>>>(attnh, woutT, bout, out);
}

// Round 4
// 264.388 us; speedup vs baseline: 6.1252x; 1.0256x over previous
//
#include <hip/hip_runtime.h>
#include <hip/hip_bf16.h>

// Problem constants
#define B_    8
#define F_    16
#define NP_   196
#define SEQ_  3137        // 1 + F_*NP_
#define H_    8
#define DH_   64
#define BH_   64          // B_*H_
#define M_    25096       // B_*SEQ_
#define MPAD_ 25216       // padded to 128-multiple (197*128)
#define DIM_  512
#define NQKV_ 1536

typedef _Float16 half8_t __attribute__((ext_vector_type(8)));
typedef _Float16 half4_t __attribute__((ext_vector_type(4)));
typedef float f32x4 __attribute__((ext_vector_type(4)));

// workspace byte offsets
#define XH_OFF     ((size_t)0)                    // [MPAD_][512] f16   25,821,184
#define WQKVT_OFF  ((size_t)25821184)             // [1536][512] f16     1,572,864
#define WOUTT_OFF  ((size_t)27394048)             // [512][512]  f16       524,288
#define QH_OFF     ((size_t)27918336)             // [64][3137][64] f16 25,698,304
#define KH_OFF     ((size_t)53616640)
#define VH_OFF     ((size_t)79314944)
#define ATTNH_OFF  ((size_t)105013248)            // [MPAD_][512] f16   25,821,184

__device__ __forceinline__ void load_lds16(const _Float16* g, _Float16* l) {
  __builtin_amdgcn_global_load_lds(
      (const __attribute__((address_space(1))) void*)g,
      (__attribute__((address_space(3))) void*)l, 16, 0, 0);
}

// ---------------------------------------------------------------------------
// conversion kernels
// ---------------------------------------------------------------------------
__global__ __launch_bounds__(256) void convert_x_kernel(
    const float* __restrict__ x, _Float16* __restrict__ xh) {
  const size_t n8 = (size_t)M_ * DIM_ / 8;
  for (size_t i = (size_t)blockIdx.x * blockDim.x + threadIdx.x; i < n8;
       i += (size_t)gridDim.x * blockDim.x) {
    float4 a = ((const float4*)x)[2 * i];
    float4 b = ((const float4*)x)[2 * i + 1];
    half8_t h;
    h[0] = (_Float16)a.x; h[1] = (_Float16)a.y; h[2] = (_Float16)a.z; h[3] = (_Float16)a.w;
    h[4] = (_Float16)b.x; h[5] = (_Float16)b.y; h[6] = (_Float16)b.z; h[7] = (_Float16)b.w;
    ((half8_t*)xh)[i] = h;
  }
}

// in [R][C] fp32 -> out [C][R] fp16  (R,C multiples of 32)
__global__ __launch_bounds__(256) void transpose_conv_kernel(
    const float* __restrict__ in, _Float16* __restrict__ out, int R, int C) {
  __shared__ float tile[32][33];
  const int r0 = blockIdx.x * 32, c0 = blockIdx.y * 32;
  const int lr = threadIdx.x >> 5, lc = threadIdx.x & 31;
#pragma unroll
  for (int p = 0; p < 4; ++p) {
    int r = p * 8 + lr;
    tile[r][lc] = in[(size_t)(r0 + r) * C + c0 + lc];
  }
  __syncthreads();
#pragma unroll
  for (int p = 0; p < 4; ++p) {
    int rr = p * 8 + lr;
    out[(size_t)(c0 + rr) * R + r0 + lc] = (_Float16)tile[lc][rr];
  }
}

// ---------------------------------------------------------------------------
// shared f16 MFMA mainloop: 128x128 tile, BK=64, 256 threads (4 waves 2x2).
// LDS XOR-swizzled (st-style): linear global_load_lds dest + pre-swizzled
// global source col ((lane&7)^(lane>>3))*8; frag reads XOR (row&7)<<3.
// Row = 128B = all 32 banks, so swizzle spreads 8 rows over the 8 16B slots
// -> 2-way residual (free). A [*][512] f16, B^T [*][512] f16.
// ---------------------------------------------------------------------------
__device__ __forceinline__ void gemm_mainloop_f16(
    const _Float16* __restrict__ A, const _Float16* __restrict__ Bt,
    int m0, int n0, _Float16* As, _Float16* Bs, f32x4 acc[4][4]) {
  const int tid = threadIdx.x;
  const int w = tid >> 6, lane = tid & 63;
  const int wr = w >> 1, wc = w & 1;
  const int lrow = lane & 15;
  const int g = lane >> 4;
  const int sw = lane & 7;                 // frag-read XOR key (x8 f16)

  // staging: per matrix 16 chunks of 1024B (8 rows x 128B); wave w: chunks 4w..4w+3
  const int srow = lane >> 3;              // row within chunk (0..7)
  const int scol = ((lane & 7) ^ srow) << 3;  // pre-swizzled global k-col (f16)

  for (int k0 = 0; k0 < DIM_; k0 += 64) {
#pragma unroll
    for (int i = 0; i < 4; ++i) {
      int c = w * 4 + i;
      int r = c * 8 + srow;
      load_lds16(A + (size_t)(m0 + r) * DIM_ + k0 + scol, As + c * 512);
      load_lds16(Bt + (size_t)(n0 + r) * DIM_ + k0 + scol, Bs + c * 512);
    }
    __syncthreads();

#pragma unroll
    for (int kk = 0; kk < 2; ++kk) {
      const int kf = ((kk * 4 + g) ^ sw) << 3;  // swizzled k-offset within row
      half8_t a[4], b[4];
#pragma unroll
      for (int m = 0; m < 4; ++m)
        a[m] = *(const half8_t*)(As + (wr * 64 + m * 16 + lrow) * 64 + kf);
#pragma unroll
      for (int n = 0; n < 4; ++n)
        b[n] = *(const half8_t*)(Bs + (wc * 64 + n * 16 + lrow) * 64 + kf);
#pragma unroll
      for (int m = 0; m < 4; ++m)
#pragma unroll
        for (int n = 0; n < 4; ++n)
          acc[m][n] = __builtin_amdgcn_mfma_f32_16x16x32_f16(a[m], b[n], acc[m][n], 0, 0, 0);
    }
    __syncthreads();
  }
}

// ---------------------------------------------------------------------------
// K1: qkv = xh @ WqkvT^T, scatter into qh/kh/vh [bh][t][64] f16, q scaled.
// ---------------------------------------------------------------------------
__global__ __launch_bounds__(256) void qkv_gemm_kernel(
    const _Float16* __restrict__ xh, const _Float16* __restrict__ wqkvT,
    _Float16* __restrict__ qh, _Float16* __restrict__ kh, _Float16* __restrict__ vh) {
  __shared__ _Float16 As[128 * 64];
  __shared__ _Float16 Bs[128 * 64];
  const int m0 = blockIdx.x * 128, n0 = blockIdx.y * 128;
  f32x4 acc[4][4];
#pragma unroll
  for (int m = 0; m < 4; ++m)
#pragma unroll
    for (int n = 0; n < 4; ++n) acc[m][n] = (f32x4)0.f;

  gemm_mainloop_f16(xh, wqkvT, m0, n0, As, Bs, acc);

  const int tid = threadIdx.x;
  const int w = tid >> 6, lane = tid & 63;
  const int wr = w >> 1, wc = w & 1;
#pragma unroll
  for (int n = 0; n < 4; ++n) {
    const int gcb = n0 + wc * 64 + n * 16;
    const int which = gcb >> 9;
    const int h = (gcb >> 6) & 7;
    const int dbase = (gcb & 63) + (lane & 15);
    const float scale = (which == 0) ? 0.125f : 1.0f;
    _Float16* dst = (which == 0) ? qh : (which == 1) ? kh : vh;
#pragma unroll
    for (int m = 0; m < 4; ++m)
#pragma unroll
      for (int j = 0; j < 4; ++j) {
        int grow = m0 + wr * 64 + m * 16 + (lane >> 4) * 4 + j;
        if (grow < M_) {
          int b = grow / SEQ_;
          int t = grow - b * SEQ_;
          dst[((size_t)(b * H_ + h) * SEQ_ + t) * DH_ + dbase] =
              (_Float16)(acc[m][n][j] * scale);
        }
      }
  }
}

// ---------------------------------------------------------------------------
// K2: CLS attention (fp16 in, fp32 math). One block per (b,h), 1024 threads.
// ---------------------------------------------------------------------------
__global__ __launch_bounds__(1024) void cls_attn_kernel(
    const _Float16* __restrict__ qh, const _Float16* __restrict__ kh,
    const _Float16* __restrict__ vh, _Float16* __restrict__ attnh) {
  const int bh = blockIdx.x;
  const int b = bh >> 3, h = bh & 7;
  const int tid = threadIdx.x;
  __shared__ float qs[64];
  __shared__ float s[SEQ_];
  __shared__ float red[1024];

  if (tid < 64) qs[tid] = (float)qh[(size_t)bh * SEQ_ * DH_ + tid];
  __syncthreads();

  float lmax = -1e30f;
  for (int j = tid; j < SEQ_; j += 1024) {
    const half8_t* kr = (const half8_t*)(kh + ((size_t)bh * SEQ_ + j) * DH_);
    float sc = 0.f;
#pragma unroll
    for (int i = 0; i < 8; ++i) {
      half8_t kk = kr[i];
#pragma unroll
      for (int u = 0; u < 8; ++u) sc += qs[8 * i + u] * (float)kk[u];
    }
    s[j] = sc;
    lmax = fmaxf(lmax, sc);
  }
  red[tid] = lmax; __syncthreads();
  for (int st = 512; st > 0; st >>= 1) {
    if (tid < st) red[tid] = fmaxf(red[tid], red[tid + st]);
    __syncthreads();
  }
  float m = red[0]; __syncthreads();

  float lsum = 0.f;
  for (int j = tid; j < SEQ_; j += 1024) {
    float p = __expf(s[j] - m);
    s[j] = p;
    lsum += p;
  }
  red[tid] = lsum; __syncthreads();
  for (int st = 512; st > 0; st >>= 1) {
    if (tid < st) red[tid] += red[tid + st];
    __syncthreads();
  }
  float l = red[0]; __syncthreads();

  const int d = tid & 63, c = tid >> 6;  // c in 0..15
  float a = 0.f;
  for (int j = c; j < SEQ_; j += 16)
    a += s[j] * (float)vh[((size_t)bh * SEQ_ + j) * DH_ + d];
  red[tid] = a; __syncthreads();
  if (tid < 64) {
    float o = 0.f;
#pragma unroll
    for (int i = 0; i < 16; ++i) o += red[i * 64 + tid];
    attnh[(size_t)(b * SEQ_) * DIM_ + h * DH_ + tid] = (_Float16)(o / l);
  }
}

// ---------------------------------------------------------------------------
// K3: frame attention, MFMA. One block per (bh, frame), 4 waves.
// ---------------------------------------------------------------------------
__global__ __launch_bounds__(256) void frame_attn_kernel(
    const _Float16* __restrict__ qh, const _Float16* __restrict__ kh,
    const _Float16* __restrict__ vh, _Float16* __restrict__ attnh) {
  const int bx = blockIdx.x;
  const int bh = bx >> 4, fi = bx & 15;
  const int b = bh >> 3, h = bh & 7;
  const int tid = threadIdx.x;
  const int w = tid >> 6, lane = tid & 63;
  const int g = lane >> 4, lc = lane & 15;

  __shared__ _Float16 VT[64 * 232];      // V^T [d][key], cols 197..231 zero
  __shared__ _Float16 Pb[4][16 * 232];   // per-wave P [q][key]
  _Float16* Pw = Pb[w];

  const size_t base = (size_t)bh * SEQ_ * DH_;

  // stage V^T (transpose-scatter), valid keys 0..196
  for (int item = tid; item < 197 * 8; item += 256) {
    int c8 = item / 197;
    int key = item - c8 * 197;
    int rowtok = (key == 0) ? 0 : fi * NP_ + key;
    half8_t hv = *(const half8_t*)(vh + base + (size_t)rowtok * DH_ + c8 * 8);
#pragma unroll
    for (int u = 0; u < 8; ++u) VT[(c8 * 8 + u) * 232 + key] = hv[u];
  }
  for (int idx = tid; idx < 64 * 35; idx += 256) {
    int d = idx / 35;
    VT[d * 232 + 197 + (idx - d * 35)] = (_Float16)0.f;
  }
#pragma unroll
  for (int z = 0; z < 4; ++z) {
    int idx = z * 64 + lane;
    Pw[(idx >> 4) * 232 + 208 + (idx & 15)] = (_Float16)0.f;
  }
  __syncthreads();

  const f32x4 zero4 = (f32x4)0.f;

  for (int qt = w; qt < 13; qt += 4) {
    int qq = qt * 16 + lc;
    int qtok = 1 + fi * NP_ + min(qq, NP_ - 1);
    const _Float16* qp = qh + base + (size_t)qtok * DH_ + g * 8;
    half8_t qb0 = *(const half8_t*)(qp);
    half8_t qb1 = *(const half8_t*)(qp + 32);

    f32x4 st[13];
#pragma unroll
    for (int t = 0; t < 13; ++t) {
      int key = t * 16 + lc;
      int rowtok = (key == 0) ? 0 : fi * NP_ + min(key, NP_);
      const _Float16* kp = kh + base + (size_t)rowtok * DH_ + g * 8;
      half8_t ka0 = *(const half8_t*)(kp);
      half8_t ka1 = *(const half8_t*)(kp + 32);
      st[t] = __builtin_amdgcn_mfma_f32_16x16x32_f16(ka0, qb0, zero4, 0, 0, 0);
      st[t] = __builtin_amdgcn_mfma_f32_16x16x32_f16(ka1, qb1, st[t], 0, 0, 0);
    }

    float mx = -1e30f;
#pragma unroll
    for (int t = 0; t < 13; ++t)
#pragma unroll
      for (int j = 0; j < 4; ++j) {
        int key = t * 16 + g * 4 + j;
        if (key >= 197) st[t][j] = -1e30f;
        mx = fmaxf(mx, st[t][j]);
      }
    mx = fmaxf(mx, __shfl_xor(mx, 16));
    mx = fmaxf(mx, __shfl_xor(mx, 32));
    float l = 0.f;
#pragma unroll
    for (int t = 0; t < 13; ++t)
#pragma unroll
      for (int j = 0; j < 4; ++j) {
        float p = __expf(st[t][j] - mx);
        st[t][j] = p;
        l += p;
      }
    l += __shfl_xor(l, 16);
    l += __shfl_xor(l, 32);
    const float inv = 1.f / l;

#pragma unroll
    for (int t = 0; t < 13; ++t) {
      half4_t hp;
#pragma unroll
      for (int j = 0; j < 4; ++j) hp[j] = (_Float16)(st[t][j] * inv);
      *(half4_t*)(Pw + lc * 232 + t * 16 + g * 4) = hp;
    }

    f32x4 o[4];
#pragma unroll
    for (int dt = 0; dt < 4; ++dt) o[dt] = zero4;
#pragma unroll
    for (int c = 0; c < 7; ++c) {
      half8_t pa = *(const half8_t*)(Pw + lc * 232 + c * 32 + g * 8);
#pragma unroll
      for (int dt = 0; dt < 4; ++dt) {
        half8_t vb = *(const half8_t*)(VT + (dt * 16 + lc) * 232 + c * 32 + g * 8);
        o[dt] = __builtin_amdgcn_mfma_f32_16x16x32_f16(pa, vb, o[dt], 0, 0, 0);
      }
    }

#pragma unroll
    for (int dt = 0; dt < 4; ++dt)
#pragma unroll
      for (int j = 0; j < 4; ++j) {
        int q = qt * 16 + g * 4 + j;
        if (q < NP_) {
          int tok = 1 + fi * NP_ + q;
          attnh[((size_t)(b * SEQ_) + tok) * DIM_ + h * DH_ + dt * 16 + lc] =
              (_Float16)o[dt][j];
        }
      }
  }
}

// ---------------------------------------------------------------------------
// K4: out = attnh @ WoutT^T + bout (fp32 out).
// ---------------------------------------------------------------------------
__global__ __launch_bounds__(256) void out_gemm_kernel(
    const _Float16* __restrict__ attnh, const _Float16* __restrict__ woutT,
    const float* __restrict__ bias, float* __restrict__ out) {
  __shared__ _Float16 As[128 * 64];
  __shared__ _Float16 Bs[128 * 64];
  const int m0 = blockIdx.x * 128, n0 = blockIdx.y * 128;
  f32x4 acc[4][4];
#pragma unroll
  for (int m = 0; m < 4; ++m)
#pragma unroll
    for (int n = 0; n < 4; ++n) acc[m][n] = (f32x4)0.f;

  gemm_mainloop_f16(attnh, woutT, m0, n0, As, Bs, acc);

  const int tid = threadIdx.x;
  const int w = tid >> 6, lane = tid & 63;
  const int wr = w >> 1, wc = w & 1;
#pragma unroll
  for (int n = 0; n < 4; ++n) {
    const int gcol = n0 + wc * 64 + n * 16 + (lane & 15);
    const float bv = bias[gcol];
#pragma unroll
    for (int m = 0; m < 4; ++m)
#pragma unroll
      for (int j = 0; j < 4; ++j) {
        int grow = m0 + wr * 64 + m * 16 + (lane >> 4) * 4 + j;
        if (grow < M_) out[(size_t)grow * DIM_ + gcol] = acc[m][n][j] + bv;
      }
  }
}

// ---------------------------------------------------------------------------
extern "C" void kernel_launch(void* const* d_in, const int* in_sizes, int n_in,
                              void* d_out, int out_size, void* d_ws, size_t ws_size,
                              hipStream_t stream) {
  (void)in_sizes; (void)n_in; (void)out_size; (void)ws_size;
  const float* x    = (const float*)d_in[0];
  const float* wqkv = (const float*)d_in[1];
  const float* wout = (const float*)d_in[2];
  const float* bout = (const float*)d_in[3];
  char* ws = (char*)d_ws;
  _Float16* xh    = (_Float16*)(ws + XH_OFF);
  _Float16* wqkvT = (_Float16*)(ws + WQKVT_OFF);
  _Float16* woutT = (_Float16*)(ws + WOUTT_OFF);
  _Float16* qh    = (_Float16*)(ws + QH_OFF);
  _Float16* kh    = (_Float16*)(ws + KH_OFF);
  _Float16* vh    = (_Float16*)(ws + VH_OFF);
  _Float16* attnh = (_Float16*)(ws + ATTNH_OFF);
  float* out = (float*)d_out;

  convert_x_kernel<<<2048, 256, 0, stream>>>(x, xh);
  {
    dim3 g(DIM_ / 32, NQKV_ / 32);
    transpose_conv_kernel<<<g, 256, 0, stream>>>(wqkv, wqkvT, DIM_, NQKV_);
  }
  {
    dim3 g(DIM_ / 32, DIM_ / 32);
    transpose_conv_kernel<<<g, 256, 0, stream>>>(wout, woutT, DIM_, DIM_);
  }

  dim3 g1(MPAD_ / 128, NQKV_ / 128);  // 197 x 12
  qkv_gemm_kernel<<<g1, 256, 0, stream>>>(xh, wqkvT, qh, kh, vh);

  cls_attn_kernel<<<BH_, 1024, 0, stream>>>(qh, kh, vh, attnh);
  frame_attn_kernel<<<BH_ * F_, 256, 0, stream>>>(qh, kh, vh, attnh);

  dim3 g2(MPAD_ / 128, DIM_ / 128);   // 197 x 4
  out_gemm_kernel<<<g2, 256, 0, stream>>>(attnh, woutT, bout, out);
}

// Round 5
// 253.986 us; speedup vs baseline: 6.3760x; 1.0410x over previous
//
#include <hip/hip_runtime.h>
#include <hip/hip_bf16.h>

// Problem constants
#define B_    8
#define F_    16
#define NP_   196
#define SEQ_  3137        // 1 + F_*NP_
#define H_    8
#define DH_   64
#define BH_   64          // B_*H_
#define M_    25096       // B_*SEQ_
#define MPAD_ 25216       // storage pad (197*128)
#define DIM_  512
#define NQKV_ 1536

typedef _Float16 half8_t __attribute__((ext_vector_type(8)));
typedef _Float16 half4_t __attribute__((ext_vector_type(4)));
typedef float f32x4 __attribute__((ext_vector_type(4)));

// workspace byte offsets
#define XH_OFF     ((size_t)0)                    // [MPAD_][512] f16   25,821,184
#define WQKVT_OFF  ((size_t)25821184)             // [1536][512] f16     1,572,864
#define WOUTT_OFF  ((size_t)27394048)             // [512][512]  f16       524,288
#define QH_OFF     ((size_t)27918336)             // [64][3137][64] f16 25,698,304
#define KH_OFF     ((size_t)53616640)
#define VH_OFF     ((size_t)79314944)
#define ATTNH_OFF  ((size_t)105013248)            // [MPAD_][512] f16   25,821,184

__device__ __forceinline__ void load_lds16(const _Float16* g, _Float16* l) {
  __builtin_amdgcn_global_load_lds(
      (const __attribute__((address_space(1))) void*)g,
      (__attribute__((address_space(3))) void*)l, 16, 0, 0);
}

// bijective XCD-chunk swizzle (m204): logical id = contiguous chunk per XCD
__device__ __forceinline__ int xcd_swz(int orig, int nwg) {
  int q = nwg >> 3, r = nwg & 7;
  int x = orig & 7, j = orig >> 3;
  return (x < r ? x * (q + 1) : r * (q + 1) + (x - r) * q) + j;
}

// ---------------------------------------------------------------------------
// conversion kernels
// ---------------------------------------------------------------------------
__global__ __launch_bounds__(256) void convert_x_kernel(
    const float* __restrict__ x, _Float16* __restrict__ xh) {
  const size_t n8 = (size_t)M_ * DIM_ / 8;
  for (size_t i = (size_t)blockIdx.x * blockDim.x + threadIdx.x; i < n8;
       i += (size_t)gridDim.x * blockDim.x) {
    float4 a = ((const float4*)x)[2 * i];
    float4 b = ((const float4*)x)[2 * i + 1];
    half8_t h;
    h[0] = (_Float16)a.x; h[1] = (_Float16)a.y; h[2] = (_Float16)a.z; h[3] = (_Float16)a.w;
    h[4] = (_Float16)b.x; h[5] = (_Float16)b.y; h[6] = (_Float16)b.z; h[7] = (_Float16)b.w;
    ((half8_t*)xh)[i] = h;
  }
}

// in [R][C] fp32 -> out [C][R] fp16  (R,C multiples of 32)
__global__ __launch_bounds__(256) void transpose_conv_kernel(
    const float* __restrict__ in, _Float16* __restrict__ out, int R, int C) {
  __shared__ float tile[32][33];
  const int r0 = blockIdx.x * 32, c0 = blockIdx.y * 32;
  const int lr = threadIdx.x >> 5, lc = threadIdx.x & 31;
#pragma unroll
  for (int p = 0; p < 4; ++p) {
    int r = p * 8 + lr;
    tile[r][lc] = in[(size_t)(r0 + r) * C + c0 + lc];
  }
  __syncthreads();
#pragma unroll
  for (int p = 0; p < 4; ++p) {
    int rr = p * 8 + lr;
    out[(size_t)(c0 + rr) * R + r0 + lc] = (_Float16)tile[lc][rr];
  }
}

// ---------------------------------------------------------------------------
// 256x256 tile, BK=64, 512 threads (8 waves 2x4), double-buffered LDS with
// prefetch-before-compute (T3 minimum-2-phase). LDS rows are 128B (=32 banks)
// so frag reads use the XOR slot swizzle; global source col pre-swizzled so
// global_load_lds dest stays linear (rule #21).
// ---------------------------------------------------------------------------
__device__ __forceinline__ void stage256(
    const _Float16* __restrict__ A, const _Float16* __restrict__ Bt,
    int m0, int n0, int k0, int maxA, _Float16* Aw, _Float16* Bw,
    int w, int srow, int scol) {
#pragma unroll
  for (int i = 0; i < 4; ++i) {
    int rloc = i * 64 + w * 8 + srow;
    int ra = min(m0 + rloc, maxA);
    load_lds16(A + (size_t)ra * DIM_ + k0 + scol, Aw + (i * 64 + w * 8) * 64);
    load_lds16(Bt + (size_t)(n0 + rloc) * DIM_ + k0 + scol, Bw + (i * 64 + w * 8) * 64);
  }
}

__device__ __forceinline__ void compute256(
    const _Float16* __restrict__ Ar, const _Float16* __restrict__ Br,
    int wr, int wc, int lrow, int g, f32x4 acc[8][4]) {
  const int xk = lrow & 7;
#pragma unroll
  for (int kk = 0; kk < 2; ++kk) {
    const int sl = ((kk * 4 + g) ^ xk) << 3;
    half8_t a[8], b[4];
#pragma unroll
    for (int n = 0; n < 4; ++n)
      b[n] = *(const half8_t*)(Br + (wc * 64 + n * 16 + lrow) * 64 + sl);
#pragma unroll
    for (int m = 0; m < 8; ++m)
      a[m] = *(const half8_t*)(Ar + (wr * 128 + m * 16 + lrow) * 64 + sl);
#pragma unroll
    for (int m = 0; m < 8; ++m)
#pragma unroll
      for (int n = 0; n < 4; ++n)
        acc[m][n] = __builtin_amdgcn_mfma_f32_16x16x32_f16(a[m], b[n], acc[m][n], 0, 0, 0);
  }
}

__device__ __forceinline__ void gemm256_mainloop(
    const _Float16* __restrict__ A, const _Float16* __restrict__ Bt,
    int m0, int n0, int maxA, _Float16* As0, _Float16* As1,
    _Float16* Bs0, _Float16* Bs1, f32x4 acc[8][4]) {
  const int tid = threadIdx.x;
  const int w = tid >> 6, lane = tid & 63;
  const int wr = w >> 2, wc = w & 3;
  const int lrow = lane & 15, g = lane >> 4;
  const int srow = lane >> 3;
  const int scol = ((lane & 7) ^ srow) << 3;

  stage256(A, Bt, m0, n0, 0, maxA, As0, Bs0, w, srow, scol);
  __syncthreads();

  const _Float16 *Ar = As0, *Br = Bs0;
  _Float16 *Aw = As1, *Bw = Bs1;
#pragma unroll
  for (int t = 0; t < 7; ++t) {
    stage256(A, Bt, m0, n0, (t + 1) * 64, maxA, Aw, Bw, w, srow, scol);
    __builtin_amdgcn_s_setprio(1);
    compute256(Ar, Br, wr, wc, lrow, g, acc);
    __builtin_amdgcn_s_setprio(0);
    __syncthreads();
    const _Float16* tA = Ar; Ar = Aw; Aw = (_Float16*)tA;
    const _Float16* tB = Br; Br = Bw; Bw = (_Float16*)tB;
  }
  __builtin_amdgcn_s_setprio(1);
  compute256(Ar, Br, wr, wc, lrow, g, acc);
  __builtin_amdgcn_s_setprio(0);
}

// ---------------------------------------------------------------------------
// K1: qkv = xh @ WqkvT^T, scatter into qh/kh/vh [bh][t][64] f16, q scaled.
// ---------------------------------------------------------------------------
__global__ __launch_bounds__(512, 2) void qkv_gemm_kernel(
    const _Float16* __restrict__ xh, const _Float16* __restrict__ wqkvT,
    _Float16* __restrict__ qh, _Float16* __restrict__ kh, _Float16* __restrict__ vh) {
  __shared__ _Float16 As[2][256 * 64];
  __shared__ _Float16 Bs[2][256 * 64];
  const int nwg = 99 * 6;
  const int lin = xcd_swz(blockIdx.x, nwg);
  const int mb = lin / 6, nb = lin - mb * 6;
  const int m0 = mb * 256, n0 = nb * 256;

  f32x4 acc[8][4];
#pragma unroll
  for (int m = 0; m < 8; ++m)
#pragma unroll
    for (int n = 0; n < 4; ++n) acc[m][n] = (f32x4)0.f;

  gemm256_mainloop(xh, wqkvT, m0, n0, M_ - 1, As[0], As[1], Bs[0], Bs[1], acc);

  const int tid = threadIdx.x;
  const int w = tid >> 6, lane = tid & 63;
  const int wr = w >> 2, wc = w & 3;
  const int lrow = lane & 15, g = lane >> 4;
#pragma unroll
  for (int n = 0; n < 4; ++n) {
    const int gcb = n0 + wc * 64 + n * 16;
    const int which = gcb >> 9;
    const int h = (gcb >> 6) & 7;
    const int dbase = (gcb & 63) + lrow;
    const float scale = (which == 0) ? 0.125f : 1.0f;
    _Float16* dst = (which == 0) ? qh : (which == 1) ? kh : vh;
#pragma unroll
    for (int m = 0; m < 8; ++m)
#pragma unroll
      for (int j = 0; j < 4; ++j) {
        int grow = m0 + wr * 128 + m * 16 + g * 4 + j;
        if (grow < M_) {
          int b = grow / SEQ_;
          int t = grow - b * SEQ_;
          dst[((size_t)(b * H_ + h) * SEQ_ + t) * DH_ + dbase] =
              (_Float16)(acc[m][n][j] * scale);
        }
      }
  }
}

// ---------------------------------------------------------------------------
// K4: out = attnh @ WoutT^T + bout (fp32 out).
// ---------------------------------------------------------------------------
__global__ __launch_bounds__(512, 2) void out_gemm_kernel(
    const _Float16* __restrict__ attnh, const _Float16* __restrict__ woutT,
    const float* __restrict__ bias, float* __restrict__ out) {
  __shared__ _Float16 As[2][256 * 64];
  __shared__ _Float16 Bs[2][256 * 64];
  const int nwg = 99 * 2;
  const int lin = xcd_swz(blockIdx.x, nwg);
  const int mb = lin >> 1, nb = lin & 1;
  const int m0 = mb * 256, n0 = nb * 256;

  f32x4 acc[8][4];
#pragma unroll
  for (int m = 0; m < 8; ++m)
#pragma unroll
    for (int n = 0; n < 4; ++n) acc[m][n] = (f32x4)0.f;

  gemm256_mainloop(attnh, woutT, m0, n0, M_ - 1, As[0], As[1], Bs[0], Bs[1], acc);

  const int tid = threadIdx.x;
  const int w = tid >> 6, lane = tid & 63;
  const int wr = w >> 2, wc = w & 3;
  const int lrow = lane & 15, g = lane >> 4;
#pragma unroll
  for (int n = 0; n < 4; ++n) {
    const int gcol = n0 + wc * 64 + n * 16 + lrow;
    const float bv = bias[gcol];
#pragma unroll
    for (int m = 0; m < 8; ++m)
#pragma unroll
      for (int j = 0; j < 4; ++j) {
        int grow = m0 + wr * 128 + m * 16 + g * 4 + j;
        if (grow < M_) out[(size_t)grow * DIM_ + gcol] = acc[m][n][j] + bv;
      }
  }
}

// ---------------------------------------------------------------------------
// K2: CLS attention (fp16 in, fp32 math). One block per (b,h), 1024 threads.
// ---------------------------------------------------------------------------
__global__ __launch_bounds__(1024) void cls_attn_kernel(
    const _Float16* __restrict__ qh, const _Float16* __restrict__ kh,
    const _Float16* __restrict__ vh, _Float16* __restrict__ attnh) {
  const int bh = blockIdx.x;
  const int b = bh >> 3, h = bh & 7;
  const int tid = threadIdx.x;
  __shared__ float qs[64];
  __shared__ float s[SEQ_];
  __shared__ float red[1024];

  if (tid < 64) qs[tid] = (float)qh[(size_t)bh * SEQ_ * DH_ + tid];
  __syncthreads();

  float lmax = -1e30f;
  for (int j = tid; j < SEQ_; j += 1024) {
    const half8_t* kr = (const half8_t*)(kh + ((size_t)bh * SEQ_ + j) * DH_);
    float sc = 0.f;
#pragma unroll
    for (int i = 0; i < 8; ++i) {
      half8_t kk = kr[i];
#pragma unroll
      for (int u = 0; u < 8; ++u) sc += qs[8 * i + u] * (float)kk[u];
    }
    s[j] = sc;
    lmax = fmaxf(lmax, sc);
  }
  red[tid] = lmax; __syncthreads();
  for (int st = 512; st > 0; st >>= 1) {
    if (tid < st) red[tid] = fmaxf(red[tid], red[tid + st]);
    __syncthreads();
  }
  float m = red[0]; __syncthreads();

  float lsum = 0.f;
  for (int j = tid; j < SEQ_; j += 1024) {
    float p = __expf(s[j] - m);
    s[j] = p;
    lsum += p;
  }
  red[tid] = lsum; __syncthreads();
  for (int st = 512; st > 0; st >>= 1) {
    if (tid < st) red[tid] += red[tid + st];
    __syncthreads();
  }
  float l = red[0]; __syncthreads();

  const int d = tid & 63, c = tid >> 6;  // c in 0..15
  float a = 0.f;
  for (int j = c; j < SEQ_; j += 16)
    a += s[j] * (float)vh[((size_t)bh * SEQ_ + j) * DH_ + d];
  red[tid] = a; __syncthreads();
  if (tid < 64) {
    float o = 0.f;
#pragma unroll
    for (int i = 0; i < 16; ++i) o += red[i * 64 + tid];
    attnh[(size_t)(b * SEQ_) * DIM_ + h * DH_ + tid] = (_Float16)(o / l);
  }
}

// ---------------------------------------------------------------------------
// K3: frame attention, MFMA. One block per (bh, frame), 4 waves.
// ---------------------------------------------------------------------------
__global__ __launch_bounds__(256) void frame_attn_kernel(
    const _Float16* __restrict__ qh, const _Float16* __restrict__ kh,
    const _Float16* __restrict__ vh, _Float16* __restrict__ attnh) {
  const int bx = blockIdx.x;
  const int bh = bx >> 4, fi = bx & 15;
  const int b = bh >> 3, h = bh & 7;
  const int tid = threadIdx.x;
  const int w = tid >> 6, lane = tid & 63;
  const int g = lane >> 4, lc = lane & 15;

  __shared__ _Float16 VT[64 * 232];      // V^T [d][key], cols 197..231 zero
  __shared__ _Float16 Pb[4][16 * 232];   // per-wave P [q][key]
  _Float16* Pw = Pb[w];

  const size_t base = (size_t)bh * SEQ_ * DH_;

  for (int item = tid; item < 197 * 8; item += 256) {
    int c8 = item / 197;
    int key = item - c8 * 197;
    int rowtok = (key == 0) ? 0 : fi * NP_ + key;
    half8_t hv = *(const half8_t*)(vh + base + (size_t)rowtok * DH_ + c8 * 8);
#pragma unroll
    for (int u = 0; u < 8; ++u) VT[(c8 * 8 + u) * 232 + key] = hv[u];
  }
  for (int idx = tid; idx < 64 * 35; idx += 256) {
    int d = idx / 35;
    VT[d * 232 + 197 + (idx - d * 35)] = (_Float16)0.f;
  }
#pragma unroll
  for (int z = 0; z < 4; ++z) {
    int idx = z * 64 + lane;
    Pw[(idx >> 4) * 232 + 208 + (idx & 15)] = (_Float16)0.f;
  }
  __syncthreads();

  const f32x4 zero4 = (f32x4)0.f;

  for (int qt = w; qt < 13; qt += 4) {
    int qq = qt * 16 + lc;
    int qtok = 1 + fi * NP_ + min(qq, NP_ - 1);
    const _Float16* qp = qh + base + (size_t)qtok * DH_ + g * 8;
    half8_t qb0 = *(const half8_t*)(qp);
    half8_t qb1 = *(const half8_t*)(qp + 32);

    f32x4 st[13];
#pragma unroll
    for (int t = 0; t < 13; ++t) {
      int key = t * 16 + lc;
      int rowtok = (key == 0) ? 0 : fi * NP_ + min(key, NP_);
      const _Float16* kp = kh + base + (size_t)rowtok * DH_ + g * 8;
      half8_t ka0 = *(const half8_t*)(kp);
      half8_t ka1 = *(const half8_t*)(kp + 32);
      st[t] = __builtin_amdgcn_mfma_f32_16x16x32_f16(ka0, qb0, zero4, 0, 0, 0);
      st[t] = __builtin_amdgcn_mfma_f32_16x16x32_f16(ka1, qb1, st[t], 0, 0, 0);
    }

    float mx = -1e30f;
#pragma unroll
    for (int t = 0; t < 13; ++t)
#pragma unroll
      for (int j = 0; j < 4; ++j) {
        int key = t * 16 + g * 4 + j;
        if (key >= 197) st[t][j] = -1e30f;
        mx = fmaxf(mx, st[t][j]);
      }
    mx = fmaxf(mx, __shfl_xor(mx, 16));
    mx = fmaxf(mx, __shfl_xor(mx, 32));
    float l = 0.f;
#pragma unroll
    for (int t = 0; t < 13; ++t)
#pragma unroll
      for (int j = 0; j < 4; ++j) {
        float p = __expf(st[t][j] - mx);
        st[t][j] = p;
        l += p;
      }
    l += __shfl_xor(l, 16);
    l += __shfl_xor(l, 32);
    const float inv = 1.f / l;

#pragma unroll
    for (int t = 0; t < 13; ++t) {
      half4_t hp;
#pragma unroll
      for (int j = 0; j < 4; ++j) hp[j] = (_Float16)(st[t][j] * inv);
      *(half4_t*)(Pw + lc * 232 + t * 16 + g * 4) = hp;
    }

    f32x4 o[4];
#pragma unroll
    for (int dt = 0; dt < 4; ++dt) o[dt] = zero4;
#pragma unroll
    for (int c = 0; c < 7; ++c) {
      half8_t pa = *(const half8_t*)(Pw + lc * 232 + c * 32 + g * 8);
#pragma unroll
      for (int dt = 0; dt < 4; ++dt) {
        half8_t vb = *(const half8_t*)(VT + (dt * 16 + lc) * 232 + c * 32 + g * 8);
        o[dt] = __builtin_amdgcn_mfma_f32_16x16x32_f16(pa, vb, o[dt], 0, 0, 0);
      }
    }

#pragma unroll
    for (int dt = 0; dt < 4; ++dt)
#pragma unroll
      for (int j = 0; j < 4; ++j) {
        int q = qt * 16 + g * 4 + j;
        if (q < NP_) {
          int tok = 1 + fi * NP_ + q;
          attnh[((size_t)(b * SEQ_) + tok) * DIM_ + h * DH_ + dt * 16 + lc] =
              (_Float16)o[dt][j];
        }
      }
  }
}

// ---------------------------------------------------------------------------
extern "C" void kernel_launch(void* const* d_in, const int* in_sizes, int n_in,
                              void* d_out, int out_size, void* d_ws, size_t ws_size,
                              hipStream_t stream) {
  (void)in_sizes; (void)n_in; (void)out_size; (void)ws_size;
  const float* x    = (const float*)d_in[0];
  const float* wqkv = (const float*)d_in[1];
  const float* wout = (const float*)d_in[2];
  const float* bout = (const float*)d_in[3];
  char* ws = (char*)d_ws;
  _Float16* xh    = (_Float16*)(ws + XH_OFF);
  _Float16* wqkvT = (_Float16*)(ws + WQKVT_OFF);
  _Float16* woutT = (_Float16*)(ws + WOUTT_OFF);
  _Float16* qh    = (_Float16*)(ws + QH_OFF);
  _Float16* kh    = (_Float16*)(ws + KH_OFF);
  _Float16* vh    = (_Float16*)(ws + VH_OFF);
  _Float16* attnh = (_Float16*)(ws + ATTNH_OFF);
  float* out = (float*)d_out;

  convert_x_kernel<<<2048, 256, 0, stream>>>(x, xh);
  {
    dim3 g(DIM_ / 32, NQKV_ / 32);
    transpose_conv_kernel<<<g, 256, 0, stream>>>(wqkv, wqkvT, DIM_, NQKV_);
  }
  {
    dim3 g(DIM_ / 32, DIM_ / 32);
    transpose_conv_kernel<<<g, 256, 0, stream>>>(wout, woutT, DIM_, DIM_);
  }

  qkv_gemm_kernel<<<99 * 6, 512, 0, stream>>>(xh, wqkvT, qh, kh, vh);

  cls_attn_kernel<<<BH_, 1024, 0, stream>>>(qh, kh, vh, attnh);
  frame_attn_kernel<<<BH_ * F_, 256, 0, stream>>>(qh, kh, vh, attnh);

  out_gemm_kernel<<<99 * 2, 512, 0, stream>>>(attnh, woutT, bout, out);
}